// Round 10
// baseline (63.143 us; speedup 1.0000x reference)
//
#include <hip/hip_runtime.h>
#include <stdint.h>

typedef unsigned short u16;
typedef unsigned int u32;
typedef __bf16 bf16x8 __attribute__((ext_vector_type(8)));
typedef float f32x4 __attribute__((ext_vector_type(4)));

#define MFMA16 __builtin_amdgcn_mfma_f32_16x16x32_bf16

// ---------------- helpers ----------------

__device__ __forceinline__ u16 f2bf(float f) {
    u32 u = __builtin_bit_cast(u32, f);
    u32 r = (u + 0x7FFFu + ((u >> 16) & 1u)) >> 16;
    return (u16)r;
}

__device__ __forceinline__ void gload_lds16(const u16* g, u16* l) {
    __builtin_amdgcn_global_load_lds(
        (const __attribute__((address_space(1))) void*)g,
        (__attribute__((address_space(3))) void*)l,
        16, 0, 0);
}

// ================= kernel 1: merged conv_x + prep_w =================
// blocks [0, convBlocks): x fp32 -> bf16 (8 elems/thread).
// blocks [convBlocks, convBlocks+512): fused TT weight precompute ->
//   Wt[o*4+s][i] (bf16 [4096][1024]) = sum_{q,r} c0[b,w,q,s]*c1[q,c,x,r,s]*c2[r,d,y,s]
//   i=(b*128+c*8+d), o=(w*128+x*8+y); 512 blocks = (bc=128)x(part=4).

__global__ __launch_bounds__(256) void pre_kernel(const float* __restrict__ x,
                                                  const float* __restrict__ c0,
                                                  const float* __restrict__ c1,
                                                  const float* __restrict__ c2,
                                                  u16* __restrict__ xb,
                                                  u16* __restrict__ Wt,
                                                  int convBlocks, int nElem) {
    __shared__ float smem[10496];   // 41 KB: c0(256) c1(4096) c2(2048) w1(4096)
    const int t = threadIdx.x;

    if ((int)blockIdx.x < convBlocks) {
        int i = (blockIdx.x * 256 + t) * 8;
        if (i + 8 > nElem) return;
        float4 a = *reinterpret_cast<const float4*>(x + i);
        float4 b = *reinterpret_cast<const float4*>(x + i + 4);
        uint4 pk;
        pk.x = (u32)f2bf(a.x) | ((u32)f2bf(a.y) << 16);
        pk.y = (u32)f2bf(a.z) | ((u32)f2bf(a.w) << 16);
        pk.z = (u32)f2bf(b.x) | ((u32)f2bf(b.y) << 16);
        pk.w = (u32)f2bf(b.z) | ((u32)f2bf(b.w) << 16);
        *reinterpret_cast<uint4*>(xb + i) = pk;
        return;
    }

    float* l_c0 = smem;           // [w][q][s]     (slice at fixed b)
    float* l_c1 = smem + 256;     // [q][x][r][s]  (slice at fixed c)
    float* l_c2 = smem + 4352;    // [r][d][y][s]  (full)
    float* l_w1 = smem + 6400;    // [w][x][r][s]

    const int bid = blockIdx.x - convBlocks;
    const int bc = bid >> 2;      // 0..127
    const int part = bid & 3;     // 0..3 : w-pair {2p, 2p+1}
    const int b = bc >> 4, c = bc & 15;

    l_c0[t] = c0[b * 256 + t];
#pragma unroll
    for (int q = 0; q < 8; ++q) {
        l_c1[q * 512 + t]       = c1[(q * 16 + c) * 512 + t];
        l_c1[q * 512 + t + 256] = c1[(q * 16 + c) * 512 + t + 256];
    }
#pragma unroll
    for (int j = 0; j < 8; ++j) l_c2[t + 256 * j] = c2[t + 256 * j];
    __syncthreads();

    // W1[w][x][r][s] = sum_q c0[w,q,s] * c1[q,x,r,s]   (only w in {2p,2p+1})
#pragma unroll
    for (int j = 0; j < 4; ++j) {
        int idx = t + 256 * (part * 4 + j);   // ((w*16+x)*8+r)*4+s
        int s = idx & 3;
        int r = (idx >> 2) & 7;
        int xx = (idx >> 5) & 15;
        int w = idx >> 9;
        float acc = 0.f;
#pragma unroll
        for (int q = 0; q < 8; ++q)
            acc += l_c0[(w * 8 + q) * 4 + s] * l_c1[q * 512 + (xx * 8 + r) * 4 + s];
        l_w1[idx] = acc;
    }
    __syncthreads();

    // Wt[(o*4+s)][b*128+c*8+d] = sum_r W1[w,x,r,s] * c2[r,d,y,s]
#pragma unroll
    for (int j = 0; j < 4; ++j) {
        int idx = t + 256 * (part * 4 + j);   // ((w*16+x)*8+y)*4+s == o*4+s
        int s = idx & 3;
        int y = (idx >> 2) & 7;
        int xx = (idx >> 5) & 15;
        int w = idx >> 9;
        float acc[8] = {0.f, 0.f, 0.f, 0.f, 0.f, 0.f, 0.f, 0.f};
#pragma unroll
        for (int r = 0; r < 8; ++r) {
            float w1 = l_w1[((w * 16 + xx) * 8 + r) * 4 + s];
#pragma unroll
            for (int d = 0; d < 8; ++d)
                acc[d] += w1 * l_c2[((r * 8 + d) * 8 + y) * 4 + s];
        }
        uint4 pk;
        pk.x = (u32)f2bf(acc[0]) | ((u32)f2bf(acc[1]) << 16);
        pk.y = (u32)f2bf(acc[2]) | ((u32)f2bf(acc[3]) << 16);
        pk.z = (u32)f2bf(acc[4]) | ((u32)f2bf(acc[5]) << 16);
        pk.w = (u32)f2bf(acc[6]) | ((u32)f2bf(acc[7]) << 16);
        *reinterpret_cast<uint4*>(&Wt[(size_t)idx * 1024 + b * 128 + c * 8]) = pk;
    }
}

// ================= kernel 2: 256x128 tile, 2 blocks/CU GEMM =================
// C[M][N] = A[M][K] * B[N][K]^T.  A = xb, B = Wt (both bf16 [4096][1024]).
// THIS ROUND: multi-block concurrency instead of intra-block scheduling.
// 256 threads = 4 waves (2M x 2N); per-wave output 128x64 = acc[8][4]
// (same wave geometry / MFMA:ds_read ratio as before). BK=32.
// LDS = dbuf x (A 256x32 + B 128x32) bf16 = 48 KB -> TWO independent
// blocks per CU (grid 512). The two blocks share no barriers: when one
// block stages/drains/epilogues, the other's waves feed the MFMA pipe
// (m114 implicit overlap; m97's mechanism). Sync per K-step: stage next
// slot at top, vmcnt(0)+s_barrier at end. No setprio, no sched_barrier
// (measured null/negative R8/R9).
//
// LDS swizzle (row stride 32 u16 = 64 B): bank = ((row&1)<<4)|(slot<<2)|dw.
// phys_slot = logical ^ ((row>>1)&3): 16 consecutive rows sweep all 8
// (row&1, slot) combos -> 2 lanes/bank -> free (R4: measured 0 conflicts).
// Both-sides involution: linear global_load_lds dest + pre-swizzled global
// source + same XOR on ds_read.
//
// XCD swizzle (T1, bijective): grid 512 = 8 XCDs x 64; per XCD an 8x8
// rectangle of (bx, by): bx = (xcd&3)*8 + (r&7), by = (xcd>>2)*8 + (r>>3).

#define ASLOT_U16 8192   // A slot: 256 rows * 32 u16 = 16 KB
#define BSLOT_U16 4096   // B slot: 128 rows * 32 u16 =  8 KB

__global__ __launch_bounds__(256, 2) void gemm256_kernel(const u16* __restrict__ A,
                                                         const u16* __restrict__ B,
                                                         float* __restrict__ C,
                                                         int M, int N, int K) {
    __shared__ u16 As[2 * ASLOT_U16];  // 32 KB
    __shared__ u16 Bs[2 * BSLOT_U16];  // 16 KB

    const int t   = threadIdx.x;
    const int ln  = t & 63;
    const int wid = t >> 6;          // 0..3
    const int wr  = wid >> 1;        // 0..1 -> M offset wr*128
    const int wc  = wid & 1;         // 0..1 -> N offset wc*64

    // ---- XCD-aware bijective block swizzle (grid 512 = 32 bx x 16 by) ----
    const int bid = blockIdx.x;          // 0..511
    const int xcd = bid & 7;
    const int r   = bid >> 3;            // 0..63
    const int bx  = (xcd & 3) * 8 + (r & 7);     // 0..31
    const int by  = (xcd >> 2) * 8 + (r >> 3);   // 0..15
    const int m0  = by * 256;
    const int n0  = bx * 128;
    const int NT  = K >> 5;          // 32 K-steps

    // fragment addressing: koff invariant across frag index (f*16, n*16
    // steps keep (row>>1)&3 fixed since 16>>1=8, 8&3=0).
    const int frow = ln & 15;
    const int ks   = ln >> 4;                        // logical k-slot 0..3
    const int koff = (ks ^ ((frow >> 1) & 3)) * 8;   // phys slot * 8 u16

    // staging: chunk c -> row = c>>2, logical slot = (c&3) ^ ((row>>1)&3),
    // linear LDS dest c*8 u16. A: 1024 chunks (4/thread); B: 512 (2/thread).
    int arw[4], acl[4];
#pragma unroll
    for (int j = 0; j < 4; ++j) {
        int c = t + j * 256;
        arw[j] = c >> 2;
        acl[j] = (((c & 3) ^ ((arw[j] >> 1) & 3))) * 8;
    }

    f32x4 acc[8][4] = {};

#define STAGE(STEP)                                                          \
    {   const int kc_ = (STEP) * 32;                                         \
        u16* Ad_ = As + ((STEP) & 1) * ASLOT_U16;                            \
        u16* Bd_ = Bs + ((STEP) & 1) * BSLOT_U16;                            \
        _Pragma("unroll")                                                    \
        for (int j = 0; j < 4; ++j)                                          \
            gload_lds16(A + (size_t)(m0 + arw[j]) * K + kc_ + acl[j],        \
                        Ad_ + (t + j * 256) * 8);                            \
        _Pragma("unroll")                                                    \
        for (int j = 0; j < 2; ++j)                                          \
            gload_lds16(B + (size_t)(n0 + arw[j]) * K + kc_ + acl[j],        \
                        Bd_ + (t + j * 256) * 8);   }

    // ---- prologue: stage step 0 ----
    STAGE(0);
    asm volatile("s_waitcnt vmcnt(0)" ::: "memory");
    __builtin_amdgcn_s_barrier();

    for (int kt = 0; kt < NT; ++kt) {
        const u16* Ab = As + (kt & 1) * ASLOT_U16;
        const u16* Bb = Bs + (kt & 1) * BSLOT_U16;
        const bool pf = (kt + 1) < NT;

        if (pf) STAGE(kt + 1);

        bf16x8 bfr[4];
#pragma unroll
        for (int n = 0; n < 4; ++n)
            bfr[n] = *reinterpret_cast<const bf16x8*>(
                Bb + (wc * 64 + n * 16 + frow) * 32 + koff);

#pragma unroll
        for (int f = 0; f < 8; ++f) {
            bf16x8 af = *reinterpret_cast<const bf16x8*>(
                Ab + (wr * 128 + f * 16 + frow) * 32 + koff);
#pragma unroll
            for (int n = 0; n < 4; ++n)
                acc[f][n] = MFMA16(af, bfr[n], acc[f][n], 0, 0, 0);
        }

        // step boundary: own DMA resident, all-waves rendezvous, slot flip
        if (pf) asm volatile("s_waitcnt vmcnt(0)" ::: "memory");
        __builtin_amdgcn_s_barrier();
    }
#undef STAGE

    // ---- epilogue: C/D layout col=lane&15, row=(lane>>4)*4+reg ----
    const int cr = (ln >> 4) * 4;
    const int cc = ln & 15;
#pragma unroll
    for (int f = 0; f < 8; ++f) {
#pragma unroll
        for (int rr = 0; rr < 4; ++rr) {
            int row = m0 + wr * 128 + f * 16 + cr + rr;
            float* p = C + (size_t)row * N + n0 + wc * 64 + cc;
#pragma unroll
            for (int fn = 0; fn < 4; ++fn)
                p[fn * 16] = acc[f][fn][rr];
        }
    }
}

// ---------------- launch ----------------

extern "C" void kernel_launch(void* const* d_in, const int* in_sizes, int n_in,
                              void* d_out, int out_size, void* d_ws, size_t ws_size,
                              hipStream_t stream) {
    const float* x  = (const float*)d_in[0];
    const float* c0 = (const float*)d_in[1];
    const float* c1 = (const float*)d_in[2];
    const float* c2 = (const float*)d_in[3];
    float* out = (float*)d_out;

    const int K = 1024;             // input dim
    const int N = 4096;             // OUT_DIM * SUP
    const int M = in_sizes[0] / K;  // tokens = B*S

    u16* xb = (u16*)d_ws;                        // M*K bf16
    u16* Wt = (u16*)d_ws + (size_t)M * K;        // N*K bf16

    const int convBlocks = (M * K) / (256 * 8);
    pre_kernel<<<convBlocks + 512, 256, 0, stream>>>(x, c0, c1, c2, xb, Wt,
                                                     convBlocks, M * K);

    gemm256_kernel<<<(N / 128) * (M / 256), 256, 0, stream>>>(xb, Wt, out, M, N, K);
}